// Round 4
// baseline (131.730 us; speedup 1.0000x reference)
//
#include <hip/hip_runtime.h>
#include <math.h>
#include <stdint.h>

#define NTRAIN 16384
#define DIM 64
#define ODIM 8
#define BATCH 8192

typedef float f32x16 __attribute__((ext_vector_type(16)));
typedef short short8 __attribute__((ext_vector_type(8)));
typedef unsigned short u16;

// float -> bf16 bits, RNE (no NaN in this data)
static __device__ __forceinline__ u16 f2bf(float f) {
  unsigned u = __builtin_bit_cast(unsigned, f);
  u += 0x7FFFu + ((u >> 16) & 1u);
  return (u16)(u >> 16);
}
static __device__ __forceinline__ float bf2f(u16 b) {
  unsigned u = ((unsigned)b) << 16;
  return __builtin_bit_cast(float, u);
}

static __device__ __forceinline__ f32x16 mfma32(short8 a, short8 b, f32x16 c) {
  return __builtin_amdgcn_mfma_f32_32x32x16_bf16(a, b, c, 0, 0, 0);
}
// v_cvt_pk_bf16_f32: dst.lo16 = bf16(a), dst.hi16 = bf16(b)
static __device__ __forceinline__ unsigned pkbf(float a, float b) {
  unsigned d;
  asm("v_cvt_pk_bf16_f32 %0, %1, %2" : "=v"(d) : "v"(a), "v"(b));
  return d;
}
// v_exp_f32: 2^x
static __device__ __forceinline__ float ex2(float x) {
  float r;
  asm("v_exp_f32 %0, %1" : "=v"(r) : "v"(x));
  return r;
}
// v_permlane32_swap_b32: a.hi32lanes <-> b.lo32lanes
static __device__ __forceinline__ void plswap(unsigned& a, unsigned& b) {
  asm("v_permlane32_swap_b32 %0, %1" : "+v"(a), "+v"(b));
}

// ---------------------------------------------------------------------------
// norms + scaled negated beta:  b2, x2, nb2 = -beta*log2(e)
// ---------------------------------------------------------------------------
__global__ __launch_bounds__(256) void k_norm(const float* __restrict__ batches,
                                              const float* __restrict__ xt,
                                              const float* __restrict__ beta,
                                              float* __restrict__ b2,
                                              float* __restrict__ x2,
                                              float* __restrict__ nb2) {
  int i = blockIdx.x * 256 + threadIdx.x;
  if (i >= BATCH + 2 * NTRAIN) return;
  if (i >= BATCH + NTRAIN) {
    int n = i - BATCH - NTRAIN;
    nb2[n] = -beta[n] * 1.4426950408889634f;
    return;
  }
  const float* row;
  float* dst;
  if (i < BATCH) { row = batches + (size_t)i * DIM; dst = b2 + i; }
  else { row = xt + (size_t)(i - BATCH) * DIM; dst = x2 + (i - BATCH); }
  const float4* r4 = (const float4*)row;
  float s0 = 0.f, s1 = 0.f, s2 = 0.f, s3 = 0.f;
#pragma unroll
  for (int q = 0; q < DIM / 4; ++q) {
    float4 v = r4[q];
    s0 = fmaf(v.x, v.x, s0); s1 = fmaf(v.y, v.y, s1);
    s2 = fmaf(v.z, v.z, s2); s3 = fmaf(v.w, v.w, s3);
  }
  *dst = (s0 + s1) + (s2 + s3);
}

// ---------------------------------------------------------------------------
// 2*x_training -> hi/lo bf16 A-fragments (32x32x16), linear order.
// frag f = ntile*4 + ks. Lane l holds 2*x[ntile*32 + (l&31)][ks*16 + (l>>5)*8 + j].
// ---------------------------------------------------------------------------
__global__ __launch_bounds__(256) void k_xfrag(const float* __restrict__ xt,
                                               u16* __restrict__ xh,
                                               u16* __restrict__ xl) {
  int tid = blockIdx.x * 256 + threadIdx.x;  // (NTRAIN/32)*4*64 threads
  int frag = tid >> 6, lane = tid & 63;
  int ntile = frag >> 2, ks = frag & 3;
  int lr = lane & 31, hi = lane >> 5;
  const float* src = xt + (size_t)(ntile * 32 + lr) * DIM + ks * 16 + hi * 8;
  unsigned h[8], l[8];
#pragma unroll
  for (int j = 0; j < 8; ++j) {
    float v = 2.0f * src[j];
    u16 hb = f2bf(v);
    h[j] = hb;
    l[j] = f2bf(v - bf2f(hb));
  }
  uint4 uh, ul;
  uh.x = h[0] | (h[1] << 16); uh.y = h[2] | (h[3] << 16);
  uh.z = h[4] | (h[5] << 16); uh.w = h[6] | (h[7] << 16);
  ul.x = l[0] | (l[1] << 16); ul.y = l[2] | (l[3] << 16);
  ul.z = l[4] | (l[5] << 16); ul.w = l[6] | (l[7] << 16);
  ((uint4*)xh)[(size_t)frag * 64 + lane] = uh;
  ((uint4*)xl)[(size_t)frag * 64 + lane] = ul;
}

// ---------------------------------------------------------------------------
// V = [1 | y | 0pad] (32 cols) -> bf16 B-fragments (32x32x16).
// frag per 16 n. Lane l holds V[frag*16 + (l>>5)*8 + j][l&31].
// ---------------------------------------------------------------------------
__global__ __launch_bounds__(256) void k_yfrag(const float* __restrict__ yt,
                                               u16* __restrict__ yv) {
  int tid = blockIdx.x * 256 + threadIdx.x;  // (NTRAIN/16)*64 threads
  int frag = tid >> 6, lane = tid & 63;
  int col = lane & 31, hi = lane >> 5;
  int n = frag * 16 + hi * 8;
  unsigned e[8];
#pragma unroll
  for (int j = 0; j < 8; ++j) {
    float v = (col == 0) ? 1.0f : ((col < 9) ? yt[(size_t)(n + j) * ODIM + (col - 1)] : 0.0f);
    e[j] = f2bf(v);
  }
  uint4 u;
  u.x = e[0] | (e[1] << 16); u.y = e[2] | (e[3] << 16);
  u.z = e[4] | (e[5] << 16); u.w = e[6] | (e[7] << 16);
  ((uint4*)yv)[(size_t)frag * 64 + lane] = u;
}

// ---------------------------------------------------------------------------
// Pass 1: swapped-S 32x32 MFMA, zero LDS. Wave tile = 64 m (2 mt) x 32 n.
// F = 2*A.X^T - (b2+x2) via accumulator init; sq = max(-F,0);
// w = exp2(nb2 * sqrt(sq)); P->bf16 in-register via cvt_pk + permlane32_swap;
// PV += P.V (two 32x32x16, V zero-padded to 32 cols).
// ---------------------------------------------------------------------------
__global__ __launch_bounds__(256, 2) void grnn_pass1(
    const float* __restrict__ batches,
    const u16* __restrict__ xh, const u16* __restrict__ xl,
    const u16* __restrict__ yv,
    const float* __restrict__ nb2,
    const float* __restrict__ x2, const float* __restrict__ b2,
    float* __restrict__ partial, int chunk_n) {
  const int w = threadIdx.x >> 6, lane = threadIdx.x & 63;
  const int lr = lane & 31, hi = lane >> 5;
  const int mbase = blockIdx.x * 256 + w * 64;
  const int c = blockIdx.y;
  const int n0 = c * chunk_n;

  // Batch B-fragments (hi/lo), 2 m-tiles x 4 ksteps; + negated b2 per m-col.
  short8 AH[2][4], AL[2][4];
  float nb2v[2];
#pragma unroll
  for (int mt = 0; mt < 2; ++mt) {
    const int mrow = mbase + mt * 32 + lr;
    nb2v[mt] = -b2[mrow];
#pragma unroll
    for (int ks = 0; ks < 4; ++ks) {
      const float* src = batches + (size_t)mrow * DIM + ks * 16 + hi * 8;
      float4 v0 = *(const float4*)src;
      float4 v1 = *(const float4*)(src + 4);
      float vv[8] = {v0.x, v0.y, v0.z, v0.w, v1.x, v1.y, v1.z, v1.w};
      short8 hh, ll;
#pragma unroll
      for (int j = 0; j < 8; ++j) {
        u16 hb = f2bf(vv[j]);
        hh[j] = (short)hb;
        ll[j] = (short)f2bf(vv[j] - bf2f(hb));
      }
      AH[mt][ks] = hh;
      AL[mt][ks] = ll;
    }
  }

  f32x16 pv[2];
#pragma unroll
  for (int mt = 0; mt < 2; ++mt)
#pragma unroll
    for (int r = 0; r < 16; ++r) pv[mt][r] = 0.f;

  const uint4* xh4 = (const uint4*)xh;
  const uint4* xl4 = (const uint4*)xl;
  const uint4* yv4 = (const uint4*)yv;

  for (int nb = n0; nb < n0 + chunk_n; nb += 32) {
    short8 XH[4], XL[4];
    const size_t fb = (size_t)(nb >> 5) * 4;
#pragma unroll
    for (int ks = 0; ks < 4; ++ks) {
      XH[ks] = __builtin_bit_cast(short8, xh4[(fb + ks) * 64 + lane]);
      XL[ks] = __builtin_bit_cast(short8, xl4[(fb + ks) * 64 + lane]);
    }
    float4 x2q[4], bq[4];
#pragma unroll
    for (int g = 0; g < 4; ++g) {
      x2q[g] = *(const float4*)&x2[nb + 8 * g + 4 * hi];
      bq[g] = *(const float4*)&nb2[nb + 8 * g + 4 * hi];
    }
    short8 V0 = __builtin_bit_cast(short8, yv4[(size_t)(nb >> 4) * 64 + lane]);
    short8 V1 = __builtin_bit_cast(short8, yv4[(size_t)(nb >> 4) * 64 + 64 + lane]);

#pragma unroll
    for (int mt = 0; mt < 2; ++mt) {
      // Init accumulator with -(b2+x2): F = 2*a.x - b2 - x2 = -sq
      f32x16 s;
#pragma unroll
      for (int g = 0; g < 4; ++g)
#pragma unroll
        for (int r = 0; r < 4; ++r) s[4 * g + r] = nb2v[mt] - x2q[g][r];
#pragma unroll
      for (int ks = 0; ks < 4; ++ks) {
        s = mfma32(XH[ks], AH[mt][ks], s);
        s = mfma32(XL[ks], AH[mt][ks], s);
        s = mfma32(XH[ks], AL[mt][ks], s);
      }
      // w = exp2(nb2 * sqrt(max(-F, 0)))
      float wv[16];
#pragma unroll
      for (int g = 0; g < 4; ++g)
#pragma unroll
        for (int r = 0; r < 4; ++r) {
          float sq = fmaxf(-s[4 * g + r], 0.f);
          float d = __builtin_amdgcn_sqrtf(sq);
          wv[4 * g + r] = ex2(bq[g][r] * d);
        }
      // P -> bf16 A-fragments fully in-register.
      unsigned U0 = pkbf(wv[0], wv[1]),   U1 = pkbf(wv[2], wv[3]);
      unsigned U2 = pkbf(wv[4], wv[5]),   U3 = pkbf(wv[6], wv[7]);
      unsigned U4 = pkbf(wv[8], wv[9]),   U5 = pkbf(wv[10], wv[11]);
      unsigned U6 = pkbf(wv[12], wv[13]), U7 = pkbf(wv[14], wv[15]);
      plswap(U0, U2); plswap(U1, U3); plswap(U4, U6); plswap(U5, U7);
      uint4 a1 = {U0, U1, U2, U3};
      uint4 a2 = {U4, U5, U6, U7};
      pv[mt] = mfma32(__builtin_bit_cast(short8, a1), V0, pv[mt]);
      pv[mt] = mfma32(__builtin_bit_cast(short8, a2), V1, pv[mt]);
    }
  }

  // Epilogue: col 0 = sum(w), cols 1..8 = sum(w*y).
  float* pc = partial + (size_t)c * 9 * BATCH;
  if (lr < 9) {
#pragma unroll
    for (int mt = 0; mt < 2; ++mt)
#pragma unroll
      for (int r = 0; r < 16; ++r)
        pc[(size_t)lr * BATCH + (mbase + mt * 32 + (r & 3) + 8 * (r >> 2) + 4 * hi)] = pv[mt][r];
  }
}

// ---------------------------------------------------------------------------
// Pass 2: reduce chunks, divide.
// ---------------------------------------------------------------------------
__global__ __launch_bounds__(256) void grnn_pass2(const float* __restrict__ partial,
                                                  float* __restrict__ out, int nc) {
  int b = blockIdx.x * 256 + threadIdx.x;
  float s1 = 0.f;
  float s2[ODIM];
#pragma unroll
  for (int j = 0; j < ODIM; ++j) s2[j] = 0.f;
  for (int cc = 0; cc < nc; ++cc) {
    const float* p = partial + (size_t)cc * 9 * BATCH;
    s1 += p[b];
#pragma unroll
    for (int j = 0; j < ODIM; ++j) s2[j] += p[(size_t)(j + 1) * BATCH + b];
  }
  const float inv = 1.f / s1;
#pragma unroll
  for (int j = 0; j < ODIM; ++j) out[(size_t)b * ODIM + j] = s2[j] * inv;
}

// ---------------------------------------------------------------------------
extern "C" void kernel_launch(void* const* d_in, const int* in_sizes, int n_in,
                              void* d_out, int out_size, void* d_ws, size_t ws_size,
                              hipStream_t stream) {
  const float* batches = (const float*)d_in[0];  // [8192, 64]
  const float* xt      = (const float*)d_in[1];  // [16384, 64]
  const float* yt      = (const float*)d_in[2];  // [16384, 8]
  const float* beta    = (const float*)d_in[3];  // [1, 16384]
  float* out = (float*)d_out;                    // [8192, 8]

  const size_t xh_b  = (size_t)NTRAIN * DIM * 2;            // 2 MB each
  const size_t yv_b  = (size_t)(NTRAIN / 16) * 64 * 16;     // 1 MB
  const size_t x2_b  = (size_t)NTRAIN * 4;
  const size_t nb2_b = (size_t)NTRAIN * 4;
  const size_t b2_b  = (size_t)BATCH * 4;
  const size_t fixed = 2 * xh_b + yv_b + x2_b + nb2_b + b2_b;
  const size_t per_chunk = (size_t)9 * BATCH * 4;           // 288 KB

  int nc = 32;
  while (nc > 1 && fixed + (size_t)nc * per_chunk > ws_size) nc >>= 1;
  const int chunk_n = NTRAIN / nc;

  char* p = (char*)d_ws;
  u16* xh = (u16*)p;      p += xh_b;
  u16* xl = (u16*)p;      p += xh_b;
  u16* yv = (u16*)p;      p += yv_b;
  float* x2 = (float*)p;  p += x2_b;
  float* nb2 = (float*)p; p += nb2_b;
  float* b2 = (float*)p;  p += b2_b;
  float* partial = (float*)p;

  k_norm<<<(BATCH + 2 * NTRAIN + 255) / 256, 256, 0, stream>>>(batches, xt, beta, b2, x2, nb2);
  k_xfrag<<<(NTRAIN / 32) * 4 * 64 / 256, 256, 0, stream>>>(xt, xh, xl);
  k_yfrag<<<(NTRAIN / 16) * 64 / 256, 256, 0, stream>>>(yt, yv);
  grnn_pass1<<<dim3(BATCH / 256, nc), 256, 0, stream>>>(
      batches, xh, xl, yv, nb2, x2, b2, partial, chunk_n);
  grnn_pass2<<<BATCH / 256, 256, 0, stream>>>(partial, out, nc);
}

// Round 5
// 99.541 us; speedup vs baseline: 1.3234x; 1.3234x over previous
//
#include <hip/hip_runtime.h>
#include <math.h>
#include <stdint.h>

#define NTRAIN 16384
#define DIM 64
#define ODIM 8
#define BATCH 8192

typedef float f32x16 __attribute__((ext_vector_type(16)));
typedef short short8 __attribute__((ext_vector_type(8)));
typedef unsigned short u16;

// float -> bf16 bits, RNE (no NaN in this data)
static __device__ __forceinline__ u16 f2bf(float f) {
  unsigned u = __builtin_bit_cast(unsigned, f);
  u += 0x7FFFu + ((u >> 16) & 1u);
  return (u16)(u >> 16);
}
static __device__ __forceinline__ float bf2f(u16 b) {
  unsigned u = ((unsigned)b) << 16;
  return __builtin_bit_cast(float, u);
}

static __device__ __forceinline__ f32x16 mfma32(short8 a, short8 b, f32x16 c) {
  return __builtin_amdgcn_mfma_f32_32x32x16_bf16(a, b, c, 0, 0, 0);
}
// v_cvt_pk_bf16_f32: dst.lo16 = bf16(a), dst.hi16 = bf16(b)
static __device__ __forceinline__ unsigned pkbf(float a, float b) {
  unsigned d;
  asm("v_cvt_pk_bf16_f32 %0, %1, %2" : "=v"(d) : "v"(a), "v"(b));
  return d;
}
// v_exp_f32: 2^x
static __device__ __forceinline__ float ex2(float x) {
  float r;
  asm("v_exp_f32 %0, %1" : "=v"(r) : "v"(x));
  return r;
}
// v_permlane32_swap_b32: a.hi32lanes <-> b.lo32lanes
static __device__ __forceinline__ void plswap(unsigned& a, unsigned& b) {
  asm("v_permlane32_swap_b32 %0, %1" : "+v"(a), "+v"(b));
}

// ---------------------------------------------------------------------------
// Fused prep: X hi/lo fragments, V fragments, norms, -beta*log2e.
// Thread ranges: [0,131072) xfrag | [.,196608) yfrag | [.,221184) norms |
//                [.,237568) nb2.  Grid = 928 blocks of 256.
// ---------------------------------------------------------------------------
__global__ __launch_bounds__(256) void k_prep(
    const float* __restrict__ batches, const float* __restrict__ xt,
    const float* __restrict__ yt, const float* __restrict__ beta,
    u16* __restrict__ xh, u16* __restrict__ xl, u16* __restrict__ yv,
    float* __restrict__ b2, float* __restrict__ x2, float* __restrict__ nb2) {
  int tid = blockIdx.x * 256 + threadIdx.x;

  if (tid < (NTRAIN / 32) * 4 * 64) {  // X fragments (2*x, hi/lo split)
    int frag = tid >> 6, lane = tid & 63;
    int ntile = frag >> 2, ks = frag & 3;
    int lr = lane & 31, hi = lane >> 5;
    const float* src = xt + (size_t)(ntile * 32 + lr) * DIM + ks * 16 + hi * 8;
    unsigned h[8], l[8];
#pragma unroll
    for (int j = 0; j < 8; ++j) {
      float v = 2.0f * src[j];
      u16 hb = f2bf(v);
      h[j] = hb;
      l[j] = f2bf(v - bf2f(hb));
    }
    uint4 uh, ul;
    uh.x = h[0] | (h[1] << 16); uh.y = h[2] | (h[3] << 16);
    uh.z = h[4] | (h[5] << 16); uh.w = h[6] | (h[7] << 16);
    ul.x = l[0] | (l[1] << 16); ul.y = l[2] | (l[3] << 16);
    ul.z = l[4] | (l[5] << 16); ul.w = l[6] | (l[7] << 16);
    ((uint4*)xh)[(size_t)frag * 64 + lane] = uh;
    ((uint4*)xl)[(size_t)frag * 64 + lane] = ul;
    return;
  }
  tid -= (NTRAIN / 32) * 4 * 64;

  if (tid < (NTRAIN / 16) * 64) {  // V = [1 | y | 0pad] fragments
    int frag = tid >> 6, lane = tid & 63;
    int col = lane & 31, hi = lane >> 5;
    int n = frag * 16 + hi * 8;
    unsigned e[8];
#pragma unroll
    for (int j = 0; j < 8; ++j) {
      float v = (col == 0) ? 1.0f : ((col < 9) ? yt[(size_t)(n + j) * ODIM + (col - 1)] : 0.0f);
      e[j] = f2bf(v);
    }
    uint4 u;
    u.x = e[0] | (e[1] << 16); u.y = e[2] | (e[3] << 16);
    u.z = e[4] | (e[5] << 16); u.w = e[6] | (e[7] << 16);
    ((uint4*)yv)[(size_t)frag * 64 + lane] = u;
    return;
  }
  tid -= (NTRAIN / 16) * 64;

  if (tid < BATCH + NTRAIN) {  // row norms
    const float* row;
    float* dst;
    if (tid < BATCH) { row = batches + (size_t)tid * DIM; dst = b2 + tid; }
    else { row = xt + (size_t)(tid - BATCH) * DIM; dst = x2 + (tid - BATCH); }
    const float4* r4 = (const float4*)row;
    float s0 = 0.f, s1 = 0.f, s2 = 0.f, s3 = 0.f;
#pragma unroll
    for (int q = 0; q < DIM / 4; ++q) {
      float4 v = r4[q];
      s0 = fmaf(v.x, v.x, s0); s1 = fmaf(v.y, v.y, s1);
      s2 = fmaf(v.z, v.z, s2); s3 = fmaf(v.w, v.w, s3);
    }
    *dst = (s0 + s1) + (s2 + s3);
    return;
  }
  tid -= BATCH + NTRAIN;

  if (tid < NTRAIN) nb2[tid] = -beta[tid] * 1.4426950408889634f;
}

// ---------------------------------------------------------------------------
// Pass 1: swapped-S 32x32 MFMA, zero LDS, register-double-buffered X slabs,
// interleaved dual accumulator chains, loads hidden behind MFMA phase.
// ---------------------------------------------------------------------------
#define LOADX(XH_, XL_, nbv)                                                  \
  {                                                                           \
    size_t fb_ = (size_t)((nbv) >> 5) * 4;                                    \
    _Pragma("unroll")                                                         \
    for (int ks = 0; ks < 4; ++ks) {                                          \
      XH_[ks] = __builtin_bit_cast(short8, xh4[(fb_ + ks) * 64 + lane]);      \
      XL_[ks] = __builtin_bit_cast(short8, xl4[(fb_ + ks) * 64 + lane]);      \
    }                                                                         \
  }

#define TAIL(S_, MT_)                                                         \
  {                                                                           \
    float bx[16];                                                             \
    _Pragma("unroll")                                                         \
    for (int g = 0; g < 4; ++g)                                               \
      _Pragma("unroll")                                                       \
      for (int r = 0; r < 4; ++r) bx[4 * g + r] = b2v[MT_] + x2q[g][r];       \
    unsigned U[8];                                                            \
    _Pragma("unroll")                                                         \
    for (int p = 0; p < 8; ++p) {                                             \
      float t0 = fmaxf(bx[2 * p] - S_[2 * p], 0.f);                           \
      float t1 = fmaxf(bx[2 * p + 1] - S_[2 * p + 1], 0.f);                   \
      float w0 = ex2(bq[(2 * p) >> 2][(2 * p) & 3] *                          \
                     __builtin_amdgcn_sqrtf(t0));                             \
      float w1 = ex2(bq[(2 * p + 1) >> 2][(2 * p + 1) & 3] *                  \
                     __builtin_amdgcn_sqrtf(t1));                             \
      U[p] = pkbf(w0, w1);                                                    \
    }                                                                         \
    plswap(U[0], U[2]); plswap(U[1], U[3]);                                   \
    plswap(U[4], U[6]); plswap(U[5], U[7]);                                   \
    uint4 a1 = {U[0], U[1], U[2], U[3]};                                      \
    uint4 a2 = {U[4], U[5], U[6], U[7]};                                      \
    pv[MT_] = mfma32(__builtin_bit_cast(short8, a1), V0, pv[MT_]);            \
    pv[MT_] = mfma32(__builtin_bit_cast(short8, a2), V1, pv[MT_]);            \
  }

#define COMPUTE(XH_, XL_, nbv)                                                \
  {                                                                           \
    float4 x2q[4], bq[4];                                                     \
    _Pragma("unroll")                                                         \
    for (int g = 0; g < 4; ++g) {                                             \
      x2q[g] = *(const float4*)&x2[(nbv) + 8 * g + 4 * hi];                   \
      bq[g] = *(const float4*)&nb2[(nbv) + 8 * g + 4 * hi];                   \
    }                                                                         \
    short8 V0 = __builtin_bit_cast(short8, yv4[(size_t)((nbv) >> 4) * 64 + lane]); \
    short8 V1 = __builtin_bit_cast(short8, yv4[(size_t)((nbv) >> 4) * 64 + 64 + lane]); \
    f32x16 s0, s1;                                                            \
    _Pragma("unroll")                                                         \
    for (int r = 0; r < 16; ++r) { s0[r] = 0.f; s1[r] = 0.f; }                \
    __builtin_amdgcn_s_setprio(1);                                            \
    _Pragma("unroll")                                                         \
    for (int ks = 0; ks < 4; ++ks) {                                          \
      s0 = mfma32(XH_[ks], AH[0][ks], s0);                                    \
      s1 = mfma32(XH_[ks], AH[1][ks], s1);                                    \
      s0 = mfma32(XL_[ks], AH[0][ks], s0);                                    \
      s1 = mfma32(XL_[ks], AH[1][ks], s1);                                    \
      s0 = mfma32(XH_[ks], AL[0][ks], s0);                                    \
      s1 = mfma32(XH_[ks], AL[1][ks], s1);                                    \
    }                                                                         \
    __builtin_amdgcn_s_setprio(0);                                            \
    TAIL(s0, 0)                                                               \
    TAIL(s1, 1)                                                               \
  }

__global__ __launch_bounds__(256, 2) void grnn_pass1(
    const float* __restrict__ batches,
    const u16* __restrict__ xh, const u16* __restrict__ xl,
    const u16* __restrict__ yv,
    const float* __restrict__ nb2,
    const float* __restrict__ x2, const float* __restrict__ b2,
    float* __restrict__ partial, int chunk_n) {
  const int w = threadIdx.x >> 6, lane = threadIdx.x & 63;
  const int lr = lane & 31, hi = lane >> 5;
  const int mbase = blockIdx.x * 256 + w * 64;
  const int c = blockIdx.y;
  const int n0 = c * chunk_n;

  // Batch B-fragments (hi/lo), 2 m-tiles x 4 ksteps; b2 per m-col.
  short8 AH[2][4], AL[2][4];
  float b2v[2];
#pragma unroll
  for (int mt = 0; mt < 2; ++mt) {
    const int mrow = mbase + mt * 32 + lr;
    b2v[mt] = b2[mrow];
#pragma unroll
    for (int ks = 0; ks < 4; ++ks) {
      const float* src = batches + (size_t)mrow * DIM + ks * 16 + hi * 8;
      float4 v0 = *(const float4*)src;
      float4 v1 = *(const float4*)(src + 4);
      float vv[8] = {v0.x, v0.y, v0.z, v0.w, v1.x, v1.y, v1.z, v1.w};
      short8 hh, ll;
#pragma unroll
      for (int j = 0; j < 8; ++j) {
        u16 hb = f2bf(vv[j]);
        hh[j] = (short)hb;
        ll[j] = (short)f2bf(vv[j] - bf2f(hb));
      }
      AH[mt][ks] = hh;
      AL[mt][ks] = ll;
    }
  }

  f32x16 pv[2];
#pragma unroll
  for (int mt = 0; mt < 2; ++mt)
#pragma unroll
    for (int r = 0; r < 16; ++r) pv[mt][r] = 0.f;

  const uint4* xh4 = (const uint4*)xh;
  const uint4* xl4 = (const uint4*)xl;
  const uint4* yv4 = (const uint4*)yv;

  short8 XHa[4], XLa[4], XHb[4], XLb[4];
  LOADX(XHa, XLa, n0)
  for (int nb = n0; nb < n0 + chunk_n; nb += 64) {
    LOADX(XHb, XLb, nb + 32)
    COMPUTE(XHa, XLa, nb)
    const int na = (nb + 64 < n0 + chunk_n) ? nb + 64 : n0;
    LOADX(XHa, XLa, na)
    COMPUTE(XHb, XLb, nb + 32)
  }

  // Epilogue: col 0 = sum(w), cols 1..8 = sum(w*y).
  float* pc = partial + (size_t)c * 9 * BATCH;
  if (lr < 9) {
#pragma unroll
    for (int mt = 0; mt < 2; ++mt)
#pragma unroll
      for (int r = 0; r < 16; ++r)
        pc[(size_t)lr * BATCH + (mbase + mt * 32 + (r & 3) + 8 * (r >> 2) + 4 * hi)] = pv[mt][r];
  }
}

// ---------------------------------------------------------------------------
// Pass 2: reduce chunks, divide.
// ---------------------------------------------------------------------------
__global__ __launch_bounds__(256) void grnn_pass2(const float* __restrict__ partial,
                                                  float* __restrict__ out, int nc) {
  int b = blockIdx.x * 256 + threadIdx.x;
  float s1 = 0.f;
  float s2[ODIM];
#pragma unroll
  for (int j = 0; j < ODIM; ++j) s2[j] = 0.f;
  for (int cc = 0; cc < nc; ++cc) {
    const float* p = partial + (size_t)cc * 9 * BATCH;
    s1 += p[b];
#pragma unroll
    for (int j = 0; j < ODIM; ++j) s2[j] += p[(size_t)(j + 1) * BATCH + b];
  }
  const float inv = 1.f / s1;
#pragma unroll
  for (int j = 0; j < ODIM; ++j) out[(size_t)b * ODIM + j] = s2[j] * inv;
}

// ---------------------------------------------------------------------------
extern "C" void kernel_launch(void* const* d_in, const int* in_sizes, int n_in,
                              void* d_out, int out_size, void* d_ws, size_t ws_size,
                              hipStream_t stream) {
  const float* batches = (const float*)d_in[0];  // [8192, 64]
  const float* xt      = (const float*)d_in[1];  // [16384, 64]
  const float* yt      = (const float*)d_in[2];  // [16384, 8]
  const float* beta    = (const float*)d_in[3];  // [1, 16384]
  float* out = (float*)d_out;                    // [8192, 8]

  const size_t xh_b  = (size_t)NTRAIN * DIM * 2;            // 2 MB each
  const size_t yv_b  = (size_t)(NTRAIN / 16) * 64 * 16;     // 1 MB
  const size_t x2_b  = (size_t)NTRAIN * 4;
  const size_t nb2_b = (size_t)NTRAIN * 4;
  const size_t b2_b  = (size_t)BATCH * 4;
  const size_t fixed = 2 * xh_b + yv_b + x2_b + nb2_b + b2_b;
  const size_t per_chunk = (size_t)9 * BATCH * 4;           // 288 KB

  int nc = 32;
  while (nc > 1 && fixed + (size_t)nc * per_chunk > ws_size) nc >>= 1;
  const int chunk_n = NTRAIN / nc;  // multiple of 64 for all nc in {1..32}

  char* p = (char*)d_ws;
  u16* xh = (u16*)p;      p += xh_b;
  u16* xl = (u16*)p;      p += xh_b;
  u16* yv = (u16*)p;      p += yv_b;
  float* x2 = (float*)p;  p += x2_b;
  float* nb2 = (float*)p; p += nb2_b;
  float* b2 = (float*)p;  p += b2_b;
  float* partial = (float*)p;

  const int prep_threads = (NTRAIN / 32) * 4 * 64 + (NTRAIN / 16) * 64 +
                           (BATCH + NTRAIN) + NTRAIN;
  k_prep<<<(prep_threads + 255) / 256, 256, 0, stream>>>(
      batches, xt, yt, beta, xh, xl, yv, b2, x2, nb2);
  grnn_pass1<<<dim3(BATCH / 256, nc), 256, 0, stream>>>(
      batches, xh, xl, yv, nb2, x2, b2, partial, chunk_n);
  grnn_pass2<<<BATCH / 256, 256, 0, stream>>>(partial, out, nc);
}